// Round 4
// baseline (311.522 us; speedup 1.0000x reference)
//
#include <hip/hip_runtime.h>

typedef __bf16 bf16;
typedef __bf16 bf16x8 __attribute__((ext_vector_type(8)));
typedef __bf16 bf16x4 __attribute__((ext_vector_type(4)));
typedef float f32x4 __attribute__((ext_vector_type(4)));

static __device__ __forceinline__ f32x4 mfma16(bf16x8 a, bf16x8 b, f32x4 c) {
  return __builtin_amdgcn_mfma_f32_16x16x32_bf16(a, b, c, 0, 0, 0);
}

// pack 8 consecutive f32 -> bf16x8
static __device__ __forceinline__ bf16x8 pk8(f32x4 a, f32x4 b) {
  bf16x8 r;
  r[0] = (bf16)a[0]; r[1] = (bf16)a[1]; r[2] = (bf16)a[2]; r[3] = (bf16)a[3];
  r[4] = (bf16)b[0]; r[5] = (bf16)b[1]; r[6] = (bf16)b[2]; r[7] = (bf16)b[3];
  return r;
}

// ---------------------------------------------------------------- k0: rpb gather (f32 planes)
__global__ void k0_rpb(const float* __restrict__ bt, const int* __restrict__ ri,
                       float* __restrict__ rpb) {
  int t = blockIdx.x * 256 + threadIdx.x;  // 0..65535
  int idx = ri[t];
  f32x4 v = *(const f32x4*)(bt + idx * 4);
#pragma unroll
  for (int h = 0; h < 4; ++h) rpb[h * 65536 + t] = v[h];
}

// ---------------------------------------------------------------- k0w: weights -> bf16 once
__global__ void k0_w(const float* __restrict__ qw, const float* __restrict__ pw,
                     bf16* __restrict__ wqb, bf16* __restrict__ wpb) {
  int t = blockIdx.x * 256 + threadIdx.x;  // 0..65535
  if (t < 49152) wqb[t] = (bf16)qw[t];
  else wpb[t - 49152] = (bf16)pw[t - 49152];
}

// ---------------------------------------------------------------- k1: fused QKV (LDS-staged x)
// q_s:(B,H,N,32) normal; k_s:(B,H) 16KB panels pre-swizzled (row m: blk^ (m&3)^((m>>2)&3));
// vt:(B,H) panels pre-swizzled (row d: blk ^ (d&7))
__global__ void __launch_bounds__(256, 3)
k1_qkv(const float* __restrict__ x, const bf16* __restrict__ wqb,
       const float* __restrict__ qb, bf16* __restrict__ q_s,
       bf16* __restrict__ k_s, bf16* __restrict__ vt) {
  __shared__ bf16 xsm[16384];  // 128 rows x 128, 16B-block xor(row&7) swizzle
  const int tid = threadIdx.x;
  const int wv = tid >> 6, ln = tid & 15, qd = (tid >> 4) & 3;
  const int b = blockIdx.x >> 1, half = blockIdx.x & 1;
  const int rg = wv >> 1, cg = wv & 1;

  // stage x (f32 -> bf16 once)
#pragma unroll
  for (int j = 0; j < 8; ++j) {
    const int bidx = j * 256 + tid;
    const int row = bidx >> 4, c = bidx & 15;
    const float* g = x + (size_t)(b * 256 + half * 128 + row) * 128 + c * 8;
    f32x4 a = *(const f32x4*)g, b2 = *(const f32x4*)(g + 4);
    *(bf16x8*)(xsm + row * 128 + ((c ^ (row & 7)) * 8)) = pk8(a, b2);
  }
  __syncthreads();

  f32x4 acc[4][4];
  bf16x8 xfk[4];

  // ---- q (ch=0) and k (ch=1): D = W.X^T (lane holds 4 consecutive out-channels)
#pragma unroll
  for (int ch = 0; ch < 2; ++ch) {
#pragma unroll
    for (int mt = 0; mt < 4; ++mt)
#pragma unroll
      for (int nt = 0; nt < 4; ++nt) acc[mt][nt] = (f32x4){0.f, 0.f, 0.f, 0.f};
#pragma unroll
    for (int ks = 0; ks < 4; ++ks) {
#pragma unroll
      for (int nt = 0; nt < 4; ++nt) {
        const int row_l = rg * 64 + nt * 16 + ln;
        xfk[nt] = *(const bf16x8*)(xsm + row_l * 128 + (((ks * 4 + qd) ^ (ln & 7)) * 8));
      }
#pragma unroll
      for (int mt = 0; mt < 4; ++mt) {
        bf16x8 wf = *(const bf16x8*)(wqb + (size_t)(ch * 128 + cg * 64 + mt * 16 + ln) * 128 +
                                     ks * 32 + qd * 8);
#pragma unroll
        for (int nt = 0; nt < 4; ++nt) acc[mt][nt] = mfma16(wf, xfk[nt], acc[mt][nt]);
      }
    }
    const float scl = ch ? 1.0f : 0.17677669529663689f;
#pragma unroll
    for (int mt = 0; mt < 4; ++mt) {
      const int c0 = cg * 64 + mt * 16 + qd * 4;
      f32x4 b4 = *(const f32x4*)(qb + ch * 128 + c0);
      const int hh = c0 >> 5, d0 = c0 & 31;
#pragma unroll
      for (int nt = 0; nt < 4; ++nt) {
        const int nr = half * 128 + rg * 64 + nt * 16 + ln;
        bf16x4 o;
#pragma unroll
        for (int r = 0; r < 4; ++r) o[r] = (bf16)((acc[mt][nt][r] + b4[r]) * scl);
        const size_t base = (size_t)(b * 4 + hh) * 8192;
        if (ch == 0) {
          *(bf16x4*)(q_s + base + nr * 32 + d0) = o;
        } else {
          const int cb = (d0 >> 3) ^ (nr & 3) ^ ((nr >> 2) & 3);
          *(bf16x4*)(k_s + base + nr * 32 + cb * 8 + (d0 & 7)) = o;
        }
      }
    }
  }

  // ---- v: D = X.W^T (lane holds 4 consecutive rows) -> swizzled V^T panel
#pragma unroll
  for (int nt = 0; nt < 4; ++nt)
#pragma unroll
    for (int mt = 0; mt < 4; ++mt) acc[nt][mt] = (f32x4){0.f, 0.f, 0.f, 0.f};
#pragma unroll
  for (int ks = 0; ks < 4; ++ks) {
#pragma unroll
    for (int nt = 0; nt < 4; ++nt) {
      const int row_l = rg * 64 + nt * 16 + ln;
      xfk[nt] = *(const bf16x8*)(xsm + row_l * 128 + (((ks * 4 + qd) ^ (ln & 7)) * 8));
    }
#pragma unroll
    for (int mt = 0; mt < 4; ++mt) {
      bf16x8 wf = *(const bf16x8*)(wqb + (size_t)(256 + cg * 64 + mt * 16 + ln) * 128 +
                                   ks * 32 + qd * 8);
#pragma unroll
      for (int nt = 0; nt < 4; ++nt) acc[nt][mt] = mfma16(xfk[nt], wf, acc[nt][mt]);
    }
  }
#pragma unroll
  for (int nt = 0; nt < 4; ++nt)
#pragma unroll
    for (int mt = 0; mt < 4; ++mt) {
      const int c = cg * 64 + mt * 16 + ln;
      const float bb = qb[256 + c];
      const int hh = c >> 5, dd = c & 31;
      const int n0 = half * 128 + rg * 64 + nt * 16 + qd * 4;
      bf16x4 o;
#pragma unroll
      for (int r = 0; r < 4; ++r) o[r] = (bf16)(acc[nt][mt][r] + bb);
      const int p = (n0 >> 3) ^ (dd & 7);
      *(bf16x4*)(vt + (size_t)(b * 4 + hh) * 8192 + dd * 256 + p * 8 + (n0 & 7)) = o;
    }
}

// ---------------------------------------------------------------- k2: attention
// grid 1024: w = bid&63, h = (bid>>6)&3, rh = bid>>8 ; 4 waves, 1 stripe (16 q-rows) each.
// S^T = K.Q^T: lane's logits share one q-row -> softmax = 2 shfl_xor. Keys in 128-halves
// through wave-private psm (4KB/wave). LDS 48KB -> 3 blocks/CU.
__global__ void __launch_bounds__(256, 3)
k2_attn(const bf16* __restrict__ q_s, const bf16* __restrict__ k_s,
        const bf16* __restrict__ vt, const float* __restrict__ mask,
        const float* __restrict__ rpb, float* __restrict__ ao) {
  __shared__ bf16 ksm[8192];  // K panel image (pre-swizzled by k1)
  __shared__ bf16 vsm[8192];  // V^T panel image (pre-swizzled by k1)
  __shared__ bf16 psm[8192];  // 4 waves x 16 x 128 (wave-private, xor(ln&7) on 16B blocks)
  const int tid = threadIdx.x, wv = tid >> 6;
  const int ln = tid & 15, qd = (tid >> 4) & 3;
  const int w = blockIdx.x & 63, h = (blockIdx.x >> 6) & 3, rh = blockIdx.x >> 8;
  const int s = rh * 4 + wv;  // stripe 0..15
  const int swzk = qd ^ (ln & 3) ^ ((ln >> 2) & 3);

  // mask[w]+rpb[h] for this wave's stripe, packed bf16 (32 VGPR)
  bf16x4 cmb[16];
  {
    const int n = s * 16 + ln;
#pragma unroll
    for (int mt = 0; mt < 16; ++mt) {
      f32x4 m4 = *(const f32x4*)(mask + ((size_t)w * 256 + n) * 256 + mt * 16 + qd * 4);
      f32x4 r4 = *(const f32x4*)(rpb + (size_t)h * 65536 + n * 256 + mt * 16 + qd * 4);
      bf16x4 cv;
#pragma unroll
      for (int r = 0; r < 4; ++r) cv[r] = (bf16)(m4[r] + r4[r]);
      cmb[mt] = cv;
    }
  }

  bf16x8 kr[4], vr[4];
  {
    const size_t base = (size_t)(w * 4 + h) * 8192;
#pragma unroll
    for (int i = 0; i < 4; ++i) {
      kr[i] = *(const bf16x8*)(k_s + base + i * 2048 + tid * 8);
      vr[i] = *(const bf16x8*)(vt + base + i * 2048 + tid * 8);
    }
  }

  for (int ib = 0; ib < 8; ++ib) {
    const int b = w + ib * 64;
    __syncthreads();  // previous iter's LDS readers done
#pragma unroll
    for (int i = 0; i < 4; ++i) {
      *(bf16x8*)(ksm + i * 2048 + tid * 8) = kr[i];
      *(bf16x8*)(vsm + i * 2048 + tid * 8) = vr[i];
    }
    __syncthreads();  // staged data visible
    if (ib < 7) {  // prefetch next panels during compute
      const size_t base = (size_t)((w + (ib + 1) * 64) * 4 + h) * 8192;
#pragma unroll
      for (int i = 0; i < 4; ++i) {
        kr[i] = *(const bf16x8*)(k_s + base + i * 2048 + tid * 8);
        vr[i] = *(const bf16x8*)(vt + base + i * 2048 + tid * 8);
      }
    }

    bf16x8 qf = *(const bf16x8*)(q_s + (size_t)(b * 4 + h) * 8192 + (s * 16 + ln) * 32 + qd * 8);
    float sum = 0.f;
    f32x4 accO[2];
    accO[0] = (f32x4){0.f, 0.f, 0.f, 0.f};
    accO[1] = (f32x4){0.f, 0.f, 0.f, 0.f};
    bf16* pb = psm + wv * 2048 + ln * 128;

#pragma unroll
    for (int hk = 0; hk < 2; ++hk) {
      f32x4 acc[8];
#pragma unroll
      for (int i = 0; i < 8; ++i) acc[i] = (f32x4){0.f, 0.f, 0.f, 0.f};
#pragma unroll
      for (int i = 0; i < 8; ++i) {
        const int m = (hk * 8 + i) * 16 + ln;
        bf16x8 af = *(const bf16x8*)(ksm + m * 32 + swzk * 8);
        acc[i] = mfma16(af, qf, acc[i]);  // S^T: lane: key=m..+(qd*4+r), qrow=ln
      }
#pragma unroll
      for (int i = 0; i < 8; ++i) {  // exp (no max-sub: |logit| bounded)
        const int mt = hk * 8 + i;
        bf16x4 pv;
#pragma unroll
        for (int r = 0; r < 4; ++r) {
          float p = __expf(acc[i][r] + (float)cmb[mt][r]);
          sum += p;
          pv[r] = (bf16)p;
        }
        const int p16 = (i * 2 + (qd >> 1)) ^ (ln & 7);
        *(bf16x4*)(pb + p16 * 8 + (qd & 1) * 4) = pv;
      }
#pragma unroll
      for (int kt = 0; kt < 4; ++kt) {  // O += P.V (this key-half)
        bf16x8 pf = *(const bf16x8*)(pb + (((kt * 4 + qd) ^ (ln & 7)) * 8));
#pragma unroll
        for (int ct = 0; ct < 2; ++ct) {
          const int d = ct * 16 + ln;
          const int p32 = ((hk * 4 + kt) * 4 + qd) ^ (d & 7);
          bf16x8 vf = *(const bf16x8*)(vsm + d * 256 + p32 * 8);
          accO[ct] = mfma16(pf, vf, accO[ct]);
        }
      }
    }
    sum += __shfl_xor(sum, 16);
    sum += __shfl_xor(sum, 32);
    const float linv = 1.0f / sum;
#pragma unroll
    for (int r = 0; r < 4; ++r) {
      const float lb = __shfl(linv, qd * 4 + r);
      const size_t orow = (size_t)(b * 256 + s * 16 + qd * 4 + r) * 128 + h * 32;
#pragma unroll
      for (int ct = 0; ct < 2; ++ct) ao[orow + ct * 16 + ln] = accO[ct][r] * lb;
    }
  }
}

// ---------------------------------------------------------------- k3: proj (in-place on d_out, LDS-staged)
__global__ void __launch_bounds__(256, 3)
k3_proj(const float* __restrict__ xin, const bf16* __restrict__ wpb,
        const float* __restrict__ pbias, float* __restrict__ out) {
  __shared__ bf16 xsm[16384];
  const int tid = threadIdx.x;
  const int wv = tid >> 6, ln = tid & 15, qd = (tid >> 4) & 3;
  const int rg = wv >> 1, cg = wv & 1;
  const size_t row0 = (size_t)blockIdx.x * 128;

#pragma unroll
  for (int j = 0; j < 8; ++j) {
    const int bidx = j * 256 + tid;
    const int row = bidx >> 4, c = bidx & 15;
    const float* g = xin + (row0 + row) * 128 + c * 8;
    f32x4 a = *(const f32x4*)g, b2 = *(const f32x4*)(g + 4);
    *(bf16x8*)(xsm + row * 128 + ((c ^ (row & 7)) * 8)) = pk8(a, b2);
  }
  __syncthreads();  // also: all in-place reads complete before any store

  f32x4 acc[4][4];
  bf16x8 xfk[4];
#pragma unroll
  for (int mt = 0; mt < 4; ++mt)
#pragma unroll
    for (int nt = 0; nt < 4; ++nt) acc[mt][nt] = (f32x4){0.f, 0.f, 0.f, 0.f};
#pragma unroll
  for (int ks = 0; ks < 4; ++ks) {
#pragma unroll
    for (int nt = 0; nt < 4; ++nt) {
      const int row_l = rg * 64 + nt * 16 + ln;
      xfk[nt] = *(const bf16x8*)(xsm + row_l * 128 + (((ks * 4 + qd) ^ (ln & 7)) * 8));
    }
#pragma unroll
    for (int mt = 0; mt < 4; ++mt) {
      bf16x8 wf = *(const bf16x8*)(wpb + (size_t)(cg * 64 + mt * 16 + ln) * 128 +
                                   ks * 32 + qd * 8);
#pragma unroll
      for (int nt = 0; nt < 4; ++nt) acc[mt][nt] = mfma16(wf, xfk[nt], acc[mt][nt]);
    }
  }
#pragma unroll
  for (int mt = 0; mt < 4; ++mt) {
    const int c0 = cg * 64 + mt * 16 + qd * 4;
    f32x4 b4 = *(const f32x4*)(pbias + c0);
#pragma unroll
    for (int nt = 0; nt < 4; ++nt) {
      f32x4 o;
#pragma unroll
      for (int r = 0; r < 4; ++r) o[r] = acc[mt][nt][r] + b4[r];
      *(f32x4*)(out + (row0 + rg * 64 + nt * 16 + ln) * 128 + c0) = o;
    }
  }
}

// ----------------------------------------------------------------
extern "C" void kernel_launch(void* const* d_in, const int* in_sizes, int n_in,
                              void* d_out, int out_size, void* d_ws, size_t ws_size,
                              hipStream_t stream) {
  const float* x = (const float*)d_in[0];
  const float* mask = (const float*)d_in[1];
  const float* qkv_w = (const float*)d_in[2];
  const float* qkv_b = (const float*)d_in[3];
  const float* proj_w = (const float*)d_in[4];
  const float* proj_b = (const float*)d_in[5];
  const float* bias_table = (const float*)d_in[6];
  const int* rel_idx = (const int*)d_in[7];

  char* ws = (char*)d_ws;
  bf16* q_s = (bf16*)ws;                         // 33.5 MB
  bf16* k_s = (bf16*)(ws + 33554432ll);          // 33.5 MB (swizzled panels)
  bf16* vt = (bf16*)(ws + 67108864ll);           // 33.5 MB (swizzled panels)
  float* rpb = (float*)(ws + 100663296ll);       // 1 MB
  bf16* wqb = (bf16*)(ws + 101711872ll);         // 96 KB
  bf16* wpb = wqb + 49152;                       // 32 KB
  float* ao = (float*)d_out;                     // attention out f32 staged in d_out

  k0_rpb<<<dim3(256), dim3(256), 0, stream>>>(bias_table, rel_idx, rpb);
  k0_w<<<dim3(256), dim3(256), 0, stream>>>(qkv_w, proj_w, wqb, wpb);
  k1_qkv<<<dim3(1024), dim3(256), 0, stream>>>(x, wqb, qkv_b, q_s, k_s, vt);
  k2_attn<<<dim3(1024), dim3(256), 0, stream>>>(q_s, k_s, vt, mask, rpb, ao);
  k3_proj<<<dim3(1024), dim3(256), 0, stream>>>(ao, wpb, proj_b, (float*)d_out);
}